// Round 19
// baseline (69.827 us; speedup 1.0000x reference)
//
#include <hip/hip_runtime.h>
#include <math.h>

#define B 128
#define E 6
#define IN_DIM 1664
#define H_DIM 512
#define OUT_DIM 618
#define ZD 32
#define K2 544
#define GRID 256
#define NT 256

typedef __attribute__((ext_vector_type(8))) short short8;
typedef __attribute__((ext_vector_type(4))) float f32x4;
union U128 { uint4 u4; short8 s8; ushort us[8]; };

__device__ __forceinline__ ushort f2bf(float f) {   // fp32 -> bf16 RNE (r16-proven)
    uint u = __float_as_uint(f);
    u += 0x7fffu + ((u >> 16) & 1u);
    return (ushort)(u >> 16);
}
__device__ __forceinline__ uint pk2(float a, float b) {
    return (uint)f2bf(a) | ((uint)f2bf(b) << 16);
}
__device__ __forceinline__ float elu1(float x) { return x < 0.f ? expm1f(x) : x; }

__device__ __forceinline__ void ast(float* p, float v) {   // agent-scope store
    __hip_atomic_store(p, v, __ATOMIC_RELAXED, __HIP_MEMORY_SCOPE_AGENT);
}
__device__ __forceinline__ float ald(const float* p) {     // agent-scope load
    return __hip_atomic_load(p, __ATOMIC_RELAXED, __HIP_MEMORY_SCOPE_AGENT);
}

// ---------------------------------------------------------------------------
// Fence-free grid barrier. All cross-phase data moves via device-scope
// atomics (coherence-point ops) or agent-scope loads/stores (cache-bypass),
// so no __threadfence (= no L2 wb_inv storm, r8's 16us/barrier cost) is
// needed. __syncthreads() drains vmcnt(0) -> this block's atomics are
// globally performed before its arrive store. Topology: one 64B arrive slot
// per block (no sharing), single release line per phase (read-only spin).
// ---------------------------------------------------------------------------
__device__ __forceinline__ void gbar(uint* arrive, uint* release, int i) {
    __syncthreads();                   // all waves' atomics complete (vmcnt 0)
    if (blockIdx.x == 0) {
        if (threadIdx.x > 0) {         // threads 1..255 <-> blocks 1..255
            while (__hip_atomic_load(&arrive[threadIdx.x * 16],
                                     __ATOMIC_RELAXED,
                                     __HIP_MEMORY_SCOPE_AGENT) < (uint)(i + 1))
                __builtin_amdgcn_s_sleep(2);
        }
        __syncthreads();
        if (threadIdx.x == 0)
            __hip_atomic_store(&release[i * 16], 1u, __ATOMIC_RELAXED,
                               __HIP_MEMORY_SCOPE_AGENT);
    } else {
        if (threadIdx.x == 0) {
            __hip_atomic_store(&arrive[blockIdx.x * 16], (uint)(i + 1),
                               __ATOMIC_RELAXED, __HIP_MEMORY_SCOPE_AGENT);
            while (__hip_atomic_load(&release[i * 16], __ATOMIC_RELAXED,
                                     __HIP_MEMORY_SCOPE_AGENT) == 0)
                __builtin_amdgcn_s_sleep(2);
        }
        __syncthreads();
    }
}

// MFMA frag math (HW-validated r3-r18):
//  A frag: lane l -> row base+(l&15), k = 32kb+(l>>4)*8+j
//  B frag: lane l -> col n0+(l&15),   k = 32kb+(l>>4)*8+j
//  C/D: col = l&15, row = (l>>4)*4 + r
// B staging (r14): thread (tn=tid&15, tq=tid>>4) stages col n0+tn, k-pair
//  (2tq,2tq+1) as one packed uint at lane ((tq>>2)<<4)|tn, j0=(2tq)&7.

// ---------------------------------------------------------------------------
// L1 job (r16 body verbatim): 64 rows x 16 cols, KPB=4 (24 steps).
// ---------------------------------------------------------------------------
__device__ __forceinline__ void job_l1(
    const float* __restrict__ x, const float* __restrict__ coef,
    const float* __restrict__ w, float* __restrict__ y1,
    int t, int sp, ushort (*bs)[64][8])
{
    const int tid = threadIdx.x;
    const int kb0 = sp * 4;
    const int n0 = (t & 31) * 16, rowbase = (t >> 5) * 64;
    const int l = tid & 63, wv = tid >> 6;
    const int tn = tid & 15, tq = tid >> 4;
    const int lp = ((tq >> 2) << 4) | tn, j0 = (2 * tq) & 7;
    const int row = rowbase + wv * 16 + (l & 15);
    const int kq = l >> 4;

    float ce[E];
    #pragma unroll
    for (int e = 0; e < E; ++e) ce[e] = coef[row * E + e];

    float xv[4][8];
    #pragma unroll
    for (int kbi = 0; kbi < 4; ++kbi) {
        const float* p = x + (size_t)row * IN_DIM + (kb0 + kbi) * 32 + kq * 8;
        const float4 a = *reinterpret_cast<const float4*>(p);
        const float4 b = *reinterpret_cast<const float4*>(p + 4);
        xv[kbi][0] = a.x; xv[kbi][1] = a.y; xv[kbi][2] = a.z; xv[kbi][3] = a.w;
        xv[kbi][4] = b.x; xv[kbi][5] = b.y; xv[kbi][6] = b.z; xv[kbi][7] = b.w;
    }

    __syncthreads();                     // previous job's bs reads done
    #pragma unroll
    for (int bb = 0; bb < 2; ++bb) {     // 2 batches of 12 step-tiles
        float wr[12][2];
        #pragma unroll
        for (int ss = 0; ss < 12; ++ss) {
            const int s = bb * 12 + ss;
            const int e = s % E, kb = kb0 + s / E;
            const float* src = w + ((size_t)e * IN_DIM + kb * 32 + 2 * tq) * H_DIM + n0 + tn;
            wr[ss][0] = src[0];
            wr[ss][1] = src[H_DIM];
        }
        #pragma unroll
        for (int ss = 0; ss < 12; ++ss)
            *reinterpret_cast<uint*>(&bs[bb * 12 + ss][lp][j0]) =
                pk2(wr[ss][0], wr[ss][1]);
    }
    __syncthreads();

    f32x4 acc = {0.f, 0.f, 0.f, 0.f};
    #pragma unroll
    for (int s = 0; s < 24; ++s) {
        const int e = s % E, kbi = s / E;
        U128 a, b0;
        uint* au = reinterpret_cast<uint*>(&a);
        au[0] = pk2(xv[kbi][0] * ce[e], xv[kbi][1] * ce[e]);
        au[1] = pk2(xv[kbi][2] * ce[e], xv[kbi][3] * ce[e]);
        au[2] = pk2(xv[kbi][4] * ce[e], xv[kbi][5] * ce[e]);
        au[3] = pk2(xv[kbi][6] * ce[e], xv[kbi][7] * ce[e]);
        b0.u4 = *reinterpret_cast<const uint4*>(&bs[s][l][0]);
        acc = __builtin_amdgcn_mfma_f32_16x16x32_bf16(a.s8, b0.s8, acc, 0, 0, 0);
    }

    const int colB = n0 + (l & 15);
    const int rowE = rowbase + wv * 16 + ((l >> 4) << 2);
    #pragma unroll
    for (int r = 0; r < 4; ++r)
        atomicAdd(&y1[(size_t)(rowE + r) * H_DIM + colB], acc[r]);
}

// ---------------------------------------------------------------------------
// L2/L3 job (r16 body; yin reads via agent-scope loads — bypass stale L2).
// ---------------------------------------------------------------------------
template<int KPB, bool ZS, int NW, bool GUARD>
__device__ __forceinline__ void job_mid(
    const float* __restrict__ yin, const float* __restrict__ coef,
    const float* __restrict__ z, const float* __restrict__ w,
    float* __restrict__ yout, int n0, int rowbase, int kb0,
    ushort (*bs)[64][8])
{
    constexpr int NS = E * KPB;
    const int tid = threadIdx.x;
    const int l = tid & 63, wv = tid >> 6;
    const int tn = tid & 15, tq = tid >> 4;
    const int lp = ((tq >> 2) << 4) | tn, j0 = (2 * tq) & 7;
    const int row = rowbase + wv * 16 + (l & 15);
    const int kq = l >> 4;
    const bool okS = !GUARD || (n0 + tn) < NW;

    float wr[NS][2];
    #pragma unroll
    for (int s = 0; s < NS; ++s) {
        const int e = s % E, kb = kb0 + s / E;
        const float* src = w + ((size_t)e * K2 + kb * 32 + 2 * tq) * NW + n0 + tn;
        wr[s][0] = okS ? src[0] : 0.f;
        wr[s][1] = okS ? src[NW] : 0.f;
    }

    float ce[E];
    #pragma unroll
    for (int e = 0; e < E; ++e) ce[e] = coef[row * E + e];

    float v[KPB * 8];
    if (ZS) {
        const float4 a = *reinterpret_cast<const float4*>(z + row * ZD + kq * 8);
        const float4 b = *reinterpret_cast<const float4*>(z + row * ZD + kq * 8 + 4);
        v[0] = a.x; v[1] = a.y; v[2] = a.z; v[3] = a.w;
        v[4] = b.x; v[5] = b.y; v[6] = b.z; v[7] = b.w;
    } else {
        #pragma unroll
        for (int kbi = 0; kbi < KPB; ++kbi) {
            const float* p = yin + (size_t)row * H_DIM + (kb0 + kbi) * 32 + kq * 8;
            #pragma unroll
            for (int j = 0; j < 8; ++j)
                v[kbi * 8 + j] = elu1(ald(p + j));   // agent-scope (coherent)
        }
    }

    __syncthreads();                     // previous job's bs reads done
    #pragma unroll
    for (int s = 0; s < NS; ++s)
        *reinterpret_cast<uint*>(&bs[s][lp][j0]) = pk2(wr[s][0], wr[s][1]);
    __syncthreads();

    f32x4 acc = {0.f, 0.f, 0.f, 0.f};
    #pragma unroll
    for (int s = 0; s < NS; ++s) {
        const int e = s % E, kbi = s / E;
        U128 a, b0;
        uint* au = reinterpret_cast<uint*>(&a);
        au[0] = pk2(v[kbi*8+0] * ce[e], v[kbi*8+1] * ce[e]);
        au[1] = pk2(v[kbi*8+2] * ce[e], v[kbi*8+3] * ce[e]);
        au[2] = pk2(v[kbi*8+4] * ce[e], v[kbi*8+5] * ce[e]);
        au[3] = pk2(v[kbi*8+6] * ce[e], v[kbi*8+7] * ce[e]);
        b0.u4 = *reinterpret_cast<const uint4*>(&bs[s][l][0]);
        acc = __builtin_amdgcn_mfma_f32_16x16x32_bf16(a.s8, b0.s8, acc, 0, 0, 0);
    }

    const int colB = n0 + (l & 15);
    const int rowE = rowbase + wv * 16 + ((l >> 4) << 2);
    if (!GUARD || colB < NW) {
        #pragma unroll
        for (int r = 0; r < 4; ++r)
            atomicAdd(&yout[(size_t)(rowE + r) * NW + colB], acc[r]);
    }
}

// ---------------------------------------------------------------------------
// Whole network, ONE persistent dispatch: 256 blocks x 256 threads
// (co-resident: 24KB LDS -> 6 blocks/CU cap, ~96 VGPR -> fine at 1/CU).
// ---------------------------------------------------------------------------
__global__ __launch_bounds__(NT) void moe_net(
    const float* __restrict__ x, const float* __restrict__ coef,
    const float* __restrict__ z,
    const float* __restrict__ w1, const float* __restrict__ b1,
    const float* __restrict__ w2, const float* __restrict__ b2,
    const float* __restrict__ w3, const float* __restrict__ b3,
    float* y1, float* y2, uint* arrive, uint* release, float* out)
{
    __shared__ ushort bs[24][64][8];     // 24 KB, reused across phases
    const int bid = blockIdx.x, tid = threadIdx.x;
    const int gt = bid * NT + tid;       // 65536 threads total

    // ---- P0: bias init (agent-scope stores; coherent with later atomics) --
    {   // y1: 65536 elements = exactly 1 per thread
        const int b = gt >> 9, o = gt & 511;
        float v = 0.f;
        #pragma unroll
        for (int e = 0; e < E; ++e) v = fmaf(coef[b * E + e], b1[e * H_DIM + o], v);
        ast(&y1[gt], v);
    }
    {   // y2
        const int b = gt >> 9, o = gt & 511;
        float v = 0.f;
        #pragma unroll
        for (int e = 0; e < E; ++e) v = fmaf(coef[b * E + e], b2[e * H_DIM + o], v);
        ast(&y2[gt], v);
    }
    for (int i = gt; i < B * OUT_DIM; i += GRID * NT) {   // out: 79104
        const int b = i / OUT_DIM, o = i - b * OUT_DIM;
        float v = 0.f;
        #pragma unroll
        for (int e = 0; e < E; ++e) v = fmaf(coef[b * E + e], b3[e * OUT_DIM + o], v);
        ast(&out[i], v);
    }
    gbar(arrive, release, 0);

    // ---- P1: L1 gemm — 832 jobs (64 row-col tiles x 13 splits) ----
    for (int job = bid; job < 832; job += GRID)
        job_l1(x, coef, w1, y1, job & 63, job >> 6, bs);
    gbar(arrive, release, 1);

    // ---- P2: L2 gemm — 576 jobs (64 tiles x 9 splits) ----
    for (int job = bid; job < 576; job += GRID) {
        const int t = job & 63, sp = job >> 6;
        const int n0 = (t & 31) * 16, rb = (t >> 5) * 64;
        if (sp < 8)
            job_mid<2, false, H_DIM, false>(y1, coef, z, w2, y2, n0, rb, sp * 2, bs);
        else
            job_mid<1, true, H_DIM, false>(y1, coef, z, w2, y2, n0, rb, 16, bs);
    }
    gbar(arrive, release, 2);

    // ---- P3: L3 gemm — 720 jobs (80 tiles x 9 splits) ----
    for (int job = bid; job < 720; job += GRID) {
        const int t = job % 80, sp = job / 80;
        const int n0 = (t % 40) * 16, rb = (t / 40) * 64;
        if (sp < 8)
            job_mid<2, false, OUT_DIM, true>(y2, coef, z, w3, out, n0, rb, sp * 2, bs);
        else
            job_mid<1, true, OUT_DIM, true>(y2, coef, z, w3, out, n0, rb, 16, bs);
    }
}

extern "C" void kernel_launch(void* const* d_in, const int* in_sizes, int n_in,
                              void* d_out, int out_size, void* d_ws, size_t ws_size,
                              hipStream_t stream)
{
    const float* p_prev = (const float*)d_in[0];
    const float* coef   = (const float*)d_in[1];
    const float* z      = (const float*)d_in[2];
    const float* w1     = (const float*)d_in[3];
    const float* b1     = (const float*)d_in[4];
    const float* w2     = (const float*)d_in[5];
    const float* b2     = (const float*)d_in[6];
    const float* w3     = (const float*)d_in[7];
    const float* b3     = (const float*)d_in[8];
    float* out = (float*)d_out;

    // ws: arrive(16KB) | release(1KB) | y1 | y2
    char* p = (char*)d_ws;
    uint* arrive  = (uint*)p; p += GRID * 64;        // 16,384
    uint* release = (uint*)p; p += 16 * 64;          //  1,024
    float* y1 = (float*)p;    p += (size_t)B * H_DIM * 4;
    float* y2 = (float*)p;

    hipMemsetAsync(arrive, 0, GRID * 64 + 16 * 64, stream);
    moe_net<<<GRID, NT, 0, stream>>>(p_prev, coef, z, w1, b1, w2, b2, w3, b3,
                                     y1, y2, arrive, release, out);
}

// Round 20
// 40.527 us; speedup vs baseline: 1.7230x; 1.7230x over previous
//
#include <hip/hip_runtime.h>
#include <math.h>

#define B 128
#define E 6
#define IN_DIM 1664
#define H_DIM 512
#define OUT_DIM 618
#define ZD 32
#define K2 544

typedef __attribute__((ext_vector_type(8))) short short8;
typedef __attribute__((ext_vector_type(4))) float f32x4;
union U128 { uint4 u4; short8 s8; ushort us[8]; };

__device__ __forceinline__ ushort f2bf(float f) {   // fp32 -> bf16 RNE (r16-proven)
    uint u = __float_as_uint(f);
    u += 0x7fffu + ((u >> 16) & 1u);
    return (ushort)(u >> 16);
}
__device__ __forceinline__ uint pk2(float a, float b) {
    return (uint)f2bf(a) | ((uint)f2bf(b) << 16);
}
__device__ __forceinline__ float elu1(float x) { return x < 0.f ? expm1f(x) : x; }

// MFMA frag math (HW-validated r3-r19):
//  A frag: lane l -> row base+(l&15), k = 32kb+(l>>4)*8+j
//  B frag: lane l -> col n0+(l&15),   k = 32kb+(l>>4)*8+j
//  C/D: col = l&15, row = (l>>4)*4 + r
// B staging (r14): thread (tn=tid&15, tq=tid>>4) stages col n0+tn, k-pair
//  (2tq,2tq+1) as one packed uint at lane ((tq>>2)<<4)|tn, j0=(2tq)&7.
// r20 = r16 EXACTLY, except gemm1 uses per-expert accumulators: A-frag =
// bf16(x) built once (manual f2bf), expert blend in epilogue -> inner loop
// is pure ds_read+MFMA. (r17 bundled this with cvt_pk which r18 showed
// costs +3.4us alone; this isolates the accumulator scheme.)

// ---------------------------------------------------------------------------
// init_y1: y1 <- coef-blended b1.
// ---------------------------------------------------------------------------
__global__ __launch_bounds__(256) void init_y1(
    const float* __restrict__ coef, const float* __restrict__ b1,
    float* __restrict__ y1)
{
    const int t = blockIdx.x * 256 + threadIdx.x;    // 16384 = B*H_DIM/4
    const int b = t >> 7, o = (t & 127) << 2;
    float4 v = {0.f, 0.f, 0.f, 0.f};
    #pragma unroll
    for (int e = 0; e < E; ++e) {
        const float c = coef[b * E + e];
        const float4 bb = *reinterpret_cast<const float4*>(b1 + e * H_DIM + o);
        v.x = fmaf(c, bb.x, v.x); v.y = fmaf(c, bb.y, v.y);
        v.z = fmaf(c, bb.z, v.z); v.w = fmaf(c, bb.w, v.w);
    }
    *reinterpret_cast<float4*>(y1 + b * H_DIM + o) = v;
}

// ---------------------------------------------------------------------------
// gemm1: L1. Block tile 64 rows x 16 cols, KPB=4 (24 steps), grid (64, 14):
// y==0 -> bias-init slice for y2+out; y in [1,13] -> split kb0=(y-1)*4.
// A-frags: bf16(x) once per kbi (manual f2bf). Inner: pure ds_read+MFMA into
// acc[e]. Epilogue: blend acc[e] with coef, 4 atomicAdds into y1.
// ---------------------------------------------------------------------------
__global__ __launch_bounds__(256) void gemm1(
    const float* __restrict__ x,     // [B][IN_DIM]
    const float* __restrict__ coef,  // [B][E]
    const float* __restrict__ w,     // [E][IN_DIM][H_DIM]
    const float* __restrict__ b2, const float* __restrict__ b3,
    float* __restrict__ y1, float* __restrict__ y2, float* __restrict__ out)
{
    __shared__ ushort bs[24][64][8];                 // 24 KB
    const int tid = threadIdx.x;

    if (blockIdx.y == 0) {                           // ---- init slice ----
        const int t = blockIdx.x * 256 + tid;
        {
            const int b = t >> 7, o = (t & 127) << 2;
            float4 v = {0.f, 0.f, 0.f, 0.f};
            #pragma unroll
            for (int e = 0; e < E; ++e) {
                const float c = coef[b * E + e];
                const float4 bb = *reinterpret_cast<const float4*>(b2 + e * H_DIM + o);
                v.x = fmaf(c, bb.x, v.x); v.y = fmaf(c, bb.y, v.y);
                v.z = fmaf(c, bb.z, v.z); v.w = fmaf(c, bb.w, v.w);
            }
            *reinterpret_cast<float4*>(y2 + b * H_DIM + o) = v;
        }
        for (int i = t; i < B * OUT_DIM; i += 64 * 256) {
            const int b = i / OUT_DIM, o = i - b * OUT_DIM;
            float v = 0.f;
            #pragma unroll
            for (int e = 0; e < E; ++e)
                v = fmaf(coef[b * E + e], b3[e * OUT_DIM + o], v);
            out[i] = v;
        }
        return;
    }

    const int kb0 = (blockIdx.y - 1) * 4;
    const int n0 = (blockIdx.x & 31) * 16, rowbase = (blockIdx.x >> 5) * 64;
    const int l = tid & 63, wv = tid >> 6;
    const int tn = tid & 15, tq = tid >> 4;
    const int lp = ((tq >> 2) << 4) | tn, j0 = (2 * tq) & 7;
    const int rowA = rowbase + wv * 16 + (l & 15);
    const int rowE = rowbase + wv * 16 + ((l >> 4) << 2);
    const int kq = l >> 4;

    // epilogue blend coefs (issued early, consumed after MFMA stream)
    float cf[4][E];
    #pragma unroll
    for (int r = 0; r < 4; ++r)
        #pragma unroll
        for (int e = 0; e < E; ++e)
            cf[r][e] = coef[(rowE + r) * E + e];

    // A-frags: bf16(x) once per kbi (UNSCALED, manual f2bf)
    U128 ax[4];
    #pragma unroll
    for (int kbi = 0; kbi < 4; ++kbi) {
        const float* p = x + (size_t)rowA * IN_DIM + (kb0 + kbi) * 32 + kq * 8;
        const float4 a = *reinterpret_cast<const float4*>(p);
        const float4 b = *reinterpret_cast<const float4*>(p + 4);
        uint* au = reinterpret_cast<uint*>(&ax[kbi]);
        au[0] = pk2(a.x, a.y); au[1] = pk2(a.z, a.w);
        au[2] = pk2(b.x, b.y); au[3] = pk2(b.z, b.w);
    }

    // W loads + staging (2 batches of 12 step-tiles), ONE barrier
    #pragma unroll
    for (int bb = 0; bb < 2; ++bb) {
        float wr[12][2];
        #pragma unroll
        for (int ss = 0; ss < 12; ++ss) {
            const int s = bb * 12 + ss;
            const int e = s % E, kb = kb0 + s / E;
            const float* src = w + ((size_t)e * IN_DIM + kb * 32 + 2 * tq) * H_DIM + n0 + tn;
            wr[ss][0] = src[0];
            wr[ss][1] = src[H_DIM];
        }
        #pragma unroll
        for (int ss = 0; ss < 12; ++ss)
            *reinterpret_cast<uint*>(&bs[bb * 12 + ss][lp][j0]) =
                pk2(wr[ss][0], wr[ss][1]);
    }
    __syncthreads();

    // pure ds_read+MFMA stream, per-expert accumulators
    f32x4 acc[E];
    #pragma unroll
    for (int e = 0; e < E; ++e) acc[e] = {0.f, 0.f, 0.f, 0.f};
    #pragma unroll
    for (int s = 0; s < 24; ++s) {
        const int e = s % E, kbi = s / E;
        U128 b0;
        b0.u4 = *reinterpret_cast<const uint4*>(&bs[s][l][0]);
        acc[e] = __builtin_amdgcn_mfma_f32_16x16x32_bf16(ax[kbi].s8, b0.s8,
                                                         acc[e], 0, 0, 0);
    }

    const int colB = n0 + (l & 15);
    #pragma unroll
    for (int r = 0; r < 4; ++r) {
        float val = 0.f;
        #pragma unroll
        for (int e = 0; e < E; ++e) val = fmaf(cf[r][e], acc[e][r], val);
        atomicAdd(&y1[(size_t)(rowE + r) * H_DIM + colB], val);
    }
}

// ---------------------------------------------------------------------------
// gemm_mid: L2/L3 — r16 body VERBATIM. Block tile 64 x 16, 9 splits
// (8x2kb + 1 z-split). Prologue: O(1) loads (elu(yin) or raw z). All W
// tiles loaded+staged, one barrier, barrier-free MFMA stream. Epilogue:
// 4 atomicAdds/thread.
// ---------------------------------------------------------------------------
template<int KPB, bool ZS, int NW, bool GUARD>
__device__ __forceinline__ void gemm_mid_body(
    const float* __restrict__ yin,   // [B][H_DIM] accum(+bias) pre-ELU
    const float* __restrict__ coef,  // [B][E]
    const float* __restrict__ z,     // [B][ZD]
    const float* __restrict__ w,     // [E][K2][NW]
    float* __restrict__ yout,        // [B][NW] accum (bias pre-init)
    int n0, int rowbase, int kb0, ushort (*bs)[64][8])
{
    constexpr int NS = E * KPB;
    const int tid = threadIdx.x;
    const int l = tid & 63, wv = tid >> 6;
    const int tn = tid & 15, tq = tid >> 4;
    const int lp = ((tq >> 2) << 4) | tn, j0 = (2 * tq) & 7;
    const int row = rowbase + wv * 16 + (l & 15);
    const int kq = l >> 4;
    const bool okS = !GUARD || (n0 + tn) < NW;

    float wr[NS][2];
    #pragma unroll
    for (int s = 0; s < NS; ++s) {
        const int e = s % E, kb = kb0 + s / E;
        const float* src = w + ((size_t)e * K2 + kb * 32 + 2 * tq) * NW + n0 + tn;
        wr[s][0] = okS ? src[0] : 0.f;
        wr[s][1] = okS ? src[NW] : 0.f;
    }

    float ce[E];
    #pragma unroll
    for (int e = 0; e < E; ++e) ce[e] = coef[row * E + e];

    float v[KPB * 8];
    if (ZS) {
        const float4 a = *reinterpret_cast<const float4*>(z + row * ZD + kq * 8);
        const float4 b = *reinterpret_cast<const float4*>(z + row * ZD + kq * 8 + 4);
        v[0] = a.x; v[1] = a.y; v[2] = a.z; v[3] = a.w;
        v[4] = b.x; v[5] = b.y; v[6] = b.z; v[7] = b.w;
    } else {
        #pragma unroll
        for (int kbi = 0; kbi < KPB; ++kbi) {
            const float* p = yin + (size_t)row * H_DIM + (kb0 + kbi) * 32 + kq * 8;
            const float4 a = *reinterpret_cast<const float4*>(p);
            const float4 b = *reinterpret_cast<const float4*>(p + 4);
            v[kbi*8+0] = elu1(a.x); v[kbi*8+1] = elu1(a.y);
            v[kbi*8+2] = elu1(a.z); v[kbi*8+3] = elu1(a.w);
            v[kbi*8+4] = elu1(b.x); v[kbi*8+5] = elu1(b.y);
            v[kbi*8+6] = elu1(b.z); v[kbi*8+7] = elu1(b.w);
        }
    }

    #pragma unroll
    for (int s = 0; s < NS; ++s)
        *reinterpret_cast<uint*>(&bs[s][lp][j0]) = pk2(wr[s][0], wr[s][1]);
    __syncthreads();

    f32x4 acc = {0.f, 0.f, 0.f, 0.f};
    #pragma unroll
    for (int s = 0; s < NS; ++s) {
        const int e = s % E, kbi = s / E;
        U128 a, b0;
        uint* au = reinterpret_cast<uint*>(&a);
        au[0] = pk2(v[kbi*8+0] * ce[e], v[kbi*8+1] * ce[e]);
        au[1] = pk2(v[kbi*8+2] * ce[e], v[kbi*8+3] * ce[e]);
        au[2] = pk2(v[kbi*8+4] * ce[e], v[kbi*8+5] * ce[e]);
        au[3] = pk2(v[kbi*8+6] * ce[e], v[kbi*8+7] * ce[e]);
        b0.u4 = *reinterpret_cast<const uint4*>(&bs[s][l][0]);
        acc = __builtin_amdgcn_mfma_f32_16x16x32_bf16(a.s8, b0.s8, acc, 0, 0, 0);
    }

    const int colB = n0 + (l & 15);
    const int rowE = rowbase + wv * 16 + ((l >> 4) << 2);
    if (!GUARD || colB < NW) {
        #pragma unroll
        for (int r = 0; r < 4; ++r)
            atomicAdd(&yout[(size_t)(rowE + r) * NW + colB], acc[r]);
    }
}

__global__ __launch_bounds__(256) void gemm_l2(
    const float* __restrict__ y1, const float* __restrict__ coef,
    const float* __restrict__ z, const float* __restrict__ w2,
    float* __restrict__ y2)
{
    __shared__ ushort bs[12][64][8];                 // 12 KB
    const int n0 = (blockIdx.x & 31) * 16, rowbase = (blockIdx.x >> 5) * 64;
    const int sp = blockIdx.y;
    if (sp < 8)
        gemm_mid_body<2, false, H_DIM, false>(y1, coef, z, w2, y2,
                                              n0, rowbase, sp * 2, bs);
    else
        gemm_mid_body<1, true, H_DIM, false>(y1, coef, z, w2, y2,
                                             n0, rowbase, 16, bs);
}

__global__ __launch_bounds__(256) void gemm_l3(
    const float* __restrict__ y2, const float* __restrict__ coef,
    const float* __restrict__ z, const float* __restrict__ w3,
    float* __restrict__ out)
{
    __shared__ ushort bs[12][64][8];
    const int nt = blockIdx.x % 40, rt = blockIdx.x / 40;   // 40 col-tiles
    const int n0 = nt * 16, rowbase = rt * 64;
    const int sp = blockIdx.y;
    if (sp < 8)
        gemm_mid_body<2, false, OUT_DIM, true>(y2, coef, z, w3, out,
                                               n0, rowbase, sp * 2, bs);
    else
        gemm_mid_body<1, true, OUT_DIM, true>(y2, coef, z, w3, out,
                                              n0, rowbase, 16, bs);
}

extern "C" void kernel_launch(void* const* d_in, const int* in_sizes, int n_in,
                              void* d_out, int out_size, void* d_ws, size_t ws_size,
                              hipStream_t stream)
{
    const float* p_prev = (const float*)d_in[0];
    const float* coef   = (const float*)d_in[1];
    const float* z      = (const float*)d_in[2];
    const float* w1     = (const float*)d_in[3];
    const float* b1     = (const float*)d_in[4];
    const float* w2     = (const float*)d_in[5];
    const float* b2     = (const float*)d_in[6];
    const float* w3     = (const float*)d_in[7];
    const float* b3     = (const float*)d_in[8];
    float* out = (float*)d_out;

    // ws: y1 | y2 (fp32 accumulators, re-initialized every call)
    float* y1 = (float*)d_ws;            // [B][512]
    float* y2 = y1 + (size_t)B * H_DIM;  // [B][512]

    init_y1<<<64, 256, 0, stream>>>(coef, b1, y1);
    gemm1<<<dim3(64, 14), 256, 0, stream>>>(p_prev, coef, w1, b2, b3,
                                            y1, y2, out);
    gemm_l2<<<dim3(64, 9), 256, 0, stream>>>(y1, coef, z, w2, y2);
    gemm_l3<<<dim3(80, 9), 256, 0, stream>>>(y2, coef, z, w3, out);
}